// Round 10
// baseline (155.317 us; speedup 1.0000x reference)
//
#include <hip/hip_runtime.h>
#include <hip/hip_bf16.h>

// UnivariateFlowMixture: N=1e6 points, C=8 channels, L=8 layers, B=32 bins.
// Pipeline: build_tables (1 blk, + slot-index) -> grid_eval (1 thread per
// (point,channel), slot-index search, shfl neighbor, packed f16 rows) ->
// interp (1-line lerp + wave-aggregated compaction) -> exact (per entry-ch).
// Round 10: revert nontemporal stores (r9: 108us interp, +40% WRITE_SIZE —
// nt bypasses L2 write-combining on gfx950). Keep G=32768 (r9 win: grid_eval
// dropped out of top-5; 2MB table L2-resident).

#define TB 3.0f
#define NB 32
#define NC 8
#define NL 8
#define LN2 0.69314718055994530942f

#define GX0 -6.5f
#define GX1 6.5f
#define TZ 0.5f
#define TL 0.5f

#define PT_FLOATS (64 * 99)                  // 6336: 64 tables of 33|33|33
#define GP_FLOATS (PT_FLOATS + 72 + 72 + 8)  // + Sc | Bb | LJ  (6488 floats)
#define GP_BYTES  (GP_FLOATS * 4)            // 25952
#define SLOTS     128
#define SLOT_BYTES (64 * SLOTS)              // 8192 uchar
#define SLOT_OFF  GP_BYTES                   // 25952
#define CNT_OFF   (SLOT_OFF + SLOT_BYTES)    // 34144
#define TAB_OFF   34176                      // 64B-aligned (64*534)

__device__ __forceinline__ float softplusf(float v) {
    return fmaxf(v, 0.f) + log1pf(expf(-fabsf(v)));
}

__device__ __forceinline__ unsigned short f2h(float f) {
    _Float16 h = (_Float16)f;
    unsigned short u;
    __builtin_memcpy(&u, &h, 2);
    return u;
}
__device__ __forceinline__ float h2f(unsigned short u) {
    _Float16 h;
    __builtin_memcpy(&h, &u, 2);
    return (float)h;
}

__device__ __forceinline__ int bsearch32(const float* __restrict__ E, float xc) {
    int i = (xc >= E[16]) ? 16 : 0;
    i += (xc >= E[i + 8]) ? 8 : 0;
    i += (xc >= E[i + 4]) ? 4 : 0;
    i += (xc >= E[i + 2]) ? 2 : 0;
    i += (xc >= E[i + 1]) ? 1 : 0;
    return i;
}

// Tlc: [0..32] cumw edges, [33..65] cumh, [66..98] derivs (LDS or global)
__device__ __forceinline__ void spline_eval(const float* __restrict__ Tlc,
                                            float zc, float& zo, float& ldo) {
    const float* E  = Tlc;
    const float* Hc = Tlc + 33;
    const float* Dv = Tlc + 66;

    float xc = fminf(fmaxf(zc, -TB), TB);
    int i = bsearch32(E, xc);

    float xk  = E[i],  xk1 = E[i + 1];
    float yk  = Hc[i], yk1 = Hc[i + 1];
    float dk  = Dv[i], dk1 = Dv[i + 1];

    float wk    = xk1 - xk;
    float hk    = yk1 - yk;
    float invw  = __builtin_amdgcn_rcpf(wk);
    float delta = hk * invw;
    float th    = (xc - xk) * invw;
    float omt   = 1.f - th;
    float t1m   = th * omt;
    float th2   = th * th;

    float num    = hk * fmaf(delta, th2, dk * t1m);
    float den    = fmaf(fmaf(-2.f, delta, dk + dk1), t1m, delta);
    float invden = __builtin_amdgcn_rcpf(den);
    float y      = fmaf(num, invden, yk);

    float dt    = delta * t1m;
    float inner = fmaf(dk1, th2, fmaf(dk, omt * omt, dt + dt));
    float dnum  = (delta * delta) * inner;
    float r  = dnum * invden * invden;
    float ld = LN2 * __builtin_amdgcn_logf(r);

    bool inside = (zc >= -TB) && (zc <= TB);
    zo  = inside ? y : zc;
    ldo = inside ? ld : 0.f;
}

// ------- kernel 1: build tables + slot index once -> gparam/gsidx ----------
extern "C" __global__ void __launch_bounds__(256)
build_tables(const float* __restrict__ w, const float* __restrict__ h,
             const float* __restrict__ s, const float* __restrict__ bias,
             const float* __restrict__ lsc,
             float* __restrict__ gparam, unsigned char* __restrict__ gsidx,
             unsigned* __restrict__ cnt)
{
    __shared__ float T[PT_FLOATS];
    __shared__ float Sc[72], Bb[72], LJ[8];

    const int tid = threadIdx.x;

    if (tid < 64) {                       // widths -> cumw edges
        const int l = tid >> 3, c = tid & 7;
        float* cw = &T[tid * 99];
        const float* wr = w + (l * NC + c) * NB;
        float m = wr[0];
        for (int b = 1; b < NB; ++b) m = fmaxf(m, wr[b]);
        float sum = 0.f;
        for (int b = 0; b < NB; ++b) sum += expf(wr[b] - m);
        float inv = 1.f / sum;
        float acc = 0.f;
        cw[0] = -TB;
        for (int b = 0; b < NB; ++b) {
            acc += 1e-3f + (1.f - 1e-3f * NB) * (expf(wr[b] - m) * inv);
            cw[b + 1] = 6.f * acc - 3.f;
        }
        cw[NB] = TB;
    } else if (tid < 128) {               // heights -> cumh
        const int t = tid - 64;
        float* ch = &T[t * 99 + 33];
        const int l = t >> 3, c = t & 7;
        const float* hr = h + (l * NC + c) * NB;
        float m = hr[0];
        for (int b = 1; b < NB; ++b) m = fmaxf(m, hr[b]);
        float sum = 0.f;
        for (int b = 0; b < NB; ++b) sum += expf(hr[b] - m);
        float inv = 1.f / sum;
        float acc = 0.f;
        ch[0] = -TB;
        for (int b = 0; b < NB; ++b) {
            acc += 1e-3f + (1.f - 1e-3f * NB) * (expf(hr[b] - m) * inv);
            ch[b + 1] = 6.f * acc - 3.f;
        }
        ch[NB] = TB;
    } else if (tid < 192) {               // derivs
        const int t = tid - 128;
        const int l = t >> 3, c = t & 7;
        float* dv = &T[t * 99 + 66];
        const float* sr = s + (l * NC + c) * (NB - 1);
        const float cst = logf(expm1f(1.f - 1e-3f));
        const float dbound = 1e-3f + softplusf(cst);
        dv[0]  = dbound;
        dv[NB] = dbound;
        for (int k = 0; k < NB - 1; ++k)
            dv[k + 1] = 1e-3f + softplusf(sr[k]);
    }
    if (tid < 72) { Sc[tid] = expf(-lsc[tid]); Bb[tid] = bias[tid]; }
    if (tid < 8) {
        float a = 0.f;
        for (int l = 0; l <= NL; ++l) a += lsc[l * NC + tid];
        LJ[tid] = -a;
    }
    if (tid == 0) *cnt = 0u;
    __syncthreads();

    for (int k = tid; k < PT_FLOATS; k += 256) gparam[k] = T[k];
    if (tid < 72) gparam[PT_FLOATS + tid]       = Sc[tid];
    if (tid < 72) gparam[PT_FLOATS + 72 + tid]  = Bb[tid];
    if (tid < 8)  gparam[PT_FLOATS + 144 + tid] = LJ[tid];

    // slot index: bin containing each uniform slot's left edge
    for (int e = tid; e < 64 * SLOTS; e += 256) {
        const int lc = e >> 7;            // e / SLOTS
        const int sl = e & (SLOTS - 1);
        const float edge = fmaf((float)sl, 6.0f / SLOTS, -3.0f);
        gsidx[e] = (unsigned char)bsearch32(&T[lc * 99], edge);
    }
}

// ------- kernel 2: grid eval, 1 thread per (point, channel) ----------------
// wave = 8 rows x 8 channels; neighbor via shfl_down(8); writes 7 rows/wave.
// row i: per channel c at byte c*8: {h(z_i), h(dz), h(lj_i), h(dlj)}
extern "C" __global__ void __launch_bounds__(256)
grid_eval(const float* __restrict__ gparam, const unsigned char* __restrict__ gsidx,
          char* __restrict__ tabb, int G, float dx)
{
    __shared__ float T[GP_FLOATS];
    __shared__ unsigned char SIDX[64 * SLOTS];
    for (int k = threadIdx.x; k < GP_FLOATS; k += 256) T[k] = gparam[k];
    for (int k = threadIdx.x; k < 64 * SLOTS; k += 256) SIDX[k] = gsidx[k];
    __syncthreads();
    const float* ScT = T + PT_FLOATS;
    const float* BbT = ScT + 72;
    const float* LJT = BbT + 72;

    const int tid  = blockIdx.x * 256 + threadIdx.x;
    const int lane = threadIdx.x & 63;
    const int W    = tid >> 6;            // global wave id
    const int c    = lane & 7;
    const int sub  = lane >> 3;           // 0..7
    const int r    = W * 7 + sub;         // unclamped row/point id
    const int i    = min(r, G - 1);       // clamped eval point

    float z  = fmaf((float)i, dx, GX0);
    float lj = LJT[c];

#pragma unroll
    for (int l = 0; l < NL; ++l) {
        const float* E = T + (l * 8 + c) * 99;
        const float u  = (z - BbT[l * 8 + c]) * ScT[l * 8 + c];
        const float xc = fminf(fmaxf(u, -TB), TB);

        int sl = (int)fmaf(xc, (float)SLOTS / 6.0f, (float)SLOTS * 0.5f);
        sl = min(max(sl, 0), SLOTS - 1);
        int q = (int)SIDX[(l * 8 + c) * SLOTS + sl];
        if (q > 0 && xc < E[q]) --q;              // fp guard
        while (q < NB - 1 && xc >= E[q + 1]) ++q; // short march

        const float xk  = E[q];
        const float wk  = E[q + 1] - xk;
        const float yk  = E[33 + q];
        const float hk  = E[34 + q] - yk;
        const float dk  = E[66 + q];
        const float dk1 = E[67 + q];

        const float invw   = __builtin_amdgcn_rcpf(wk);
        const float delta  = hk * invw;
        const float th     = (xc - xk) * invw;
        const float omt    = 1.f - th;
        const float t1m    = th * omt;
        const float th2    = th * th;
        const float num    = hk * fmaf(delta, th2, dk * t1m);
        const float den    = fmaf(fmaf(-2.f, delta, dk + dk1), t1m, delta);
        const float invden = __builtin_amdgcn_rcpf(den);
        const float y      = fmaf(num, invden, yk);
        const float dt     = delta * t1m;
        const float inner  = fmaf(dk1, th2, fmaf(dk, omt * omt, dt + dt));
        const float rr     = (delta * delta) * inner * invden * invden;
        const bool inside  = (u >= -TB) && (u <= TB);
        z  = inside ? y : u;
        lj += inside ? LN2 * __builtin_amdgcn_logf(rr) : 0.f;
    }
    z = (z - BbT[NL * 8 + c]) * ScT[NL * 8 + c];

    const float zn  = __shfl_down(z, 8);
    const float ljn = __shfl_down(lj, 8);

    if (sub < 7 && r <= G - 2) {
        ushort4 v;
        v.x = f2h(z);  v.y = f2h(zn - z);
        v.z = f2h(lj); v.w = f2h(ljn - lj);
        *(ushort4*)(tabb + (size_t)r * 64 + c * 8) = v;
    }
}

// ---------------- kernel 3: interpolate + compact flagged points ------------
extern "C" __global__ void __launch_bounds__(256)
interp_kernel(const float* __restrict__ x, const char* __restrict__ tabb,
              const float* __restrict__ gparam, float* __restrict__ out,
              unsigned* __restrict__ cnt, unsigned* __restrict__ wl, int wlcap,
              int N, int G, float dx, float invdx)
{
    const int n = blockIdx.x * 256 + threadIdx.x;
    if (n >= N) return;

    const float xv = x[n];
    int i = (int)floorf((xv - GX0) * invdx);
    const bool oor = !(xv > GX0 && xv < GX1);
    i = min(max(i, 0), G - 2);
    const float t = (xv - fmaf((float)i, dx, GX0)) * invdx;

    const float4* rp = (const float4*)(tabb + (size_t)i * 64);
    union { float4 q[4]; unsigned int u[16]; } R;
    R.q[0] = rp[0]; R.q[1] = rp[1]; R.q[2] = rp[2]; R.q[3] = rp[3];

    float z[NC], lj[NC];
    int flags = 0;
#pragma unroll
    for (int c = 0; c < NC; ++c) {
        const unsigned a = R.u[2 * c], b = R.u[2 * c + 1];
        const float z0 = h2f((unsigned short)a);
        const float dz = h2f((unsigned short)(a >> 16));
        const float l0 = h2f((unsigned short)b);
        const float dl = h2f((unsigned short)(b >> 16));
        z[c]  = fmaf(t, dz, z0);
        lj[c] = fmaf(t, dl, l0);
        if (fabsf(dz) > TZ || fabsf(dl) > TL) flags |= (1 << c);
    }
    if (oor) flags = 0xff;

    // wave-aggregated compaction: one atomic per wave
    const unsigned long long m = __ballot(flags != 0);
    if (flags) {
        const int lane = threadIdx.x & 63;
        const int lead = __ffsll(m) - 1;
        const int rank = __popcll(m & ((1ull << lane) - 1ull));
        unsigned base = 0;
        if (lane == lead) base = atomicAdd(cnt, (unsigned)__popcll(m));
        base = __shfl(base, lead);
        const unsigned slot = base + (unsigned)rank;
        if (slot < (unsigned)wlcap) {
            wl[slot] = ((unsigned)n << 8) | (unsigned)flags;
        } else {
            // overflow (rare): exact inline from global tables
            const float* ScG = gparam + PT_FLOATS;
            const float* BbG = ScG + 72;
            const float* LJG = BbG + 72;
#pragma unroll 1
            for (int c = 0; c < NC; ++c) {
                if (!((flags >> c) & 1)) continue;
                float zc = xv;
                float lacc = LJG[c];
#pragma unroll 1
                for (int l = 0; l < NL; ++l) {
                    zc = (zc - BbG[l * 8 + c]) * ScG[l * 8 + c];
                    float ld;
                    spline_eval(gparam + (l * 8 + c) * 99, zc, zc, ld);
                    lacc += ld;
                }
                z[c]  = (zc - BbG[NL * 8 + c]) * ScG[NL * 8 + c];
                lj[c] = lacc;
            }
        }
    }

    float4* oz = (float4*)(out + (size_t)n * NC);
    oz[0] = make_float4(z[0], z[1], z[2], z[3]);
    oz[1] = make_float4(z[4], z[5], z[6], z[7]);
    float4* ol = (float4*)(out + (size_t)N * NC + (size_t)n * NC);
    ol[0] = make_float4(lj[0], lj[1], lj[2], lj[3]);
    ol[1] = make_float4(lj[4], lj[5], lj[6], lj[7]);
}

// -------- kernel 4: exact pass, one thread per (entry, channel) -------------
extern "C" __global__ void __launch_bounds__(256)
exact_kernel(const float* __restrict__ x, const float* __restrict__ gparam,
             const unsigned* __restrict__ cnt, const unsigned* __restrict__ wl,
             int wlcap, float* __restrict__ out, int N)
{
    __shared__ float T[GP_FLOATS];
    for (int k = threadIdx.x; k < GP_FLOATS; k += 256) T[k] = gparam[k];
    __syncthreads();
    const float* ScT = T + PT_FLOATS;
    const float* BbT = ScT + 72;
    const float* LJT = BbT + 72;

    const unsigned count  = min(*cnt, (unsigned)wlcap);
    const unsigned total  = count * 8u;
    const unsigned stride = gridDim.x * 256u;
    for (unsigned u = blockIdx.x * 256u + threadIdx.x; u < total; u += stride) {
        const unsigned e = u >> 3;
        const int      c = (int)(u & 7u);
        const unsigned ent = wl[e];
        if (!((ent >> c) & 1u)) continue;          // flags = low 8 bits
        const int n = (int)(ent >> 8);
        if (n >= N) continue;                      // defensive
        const float xv = x[n];
        float zc = xv;
        float lacc = LJT[c];
#pragma unroll 1
        for (int l = 0; l < NL; ++l) {
            zc = (zc - BbT[l * 8 + c]) * ScT[l * 8 + c];
            float ld;
            spline_eval(T + (l * 8 + c) * 99, zc, zc, ld);
            lacc += ld;
        }
        zc = (zc - BbT[NL * 8 + c]) * ScT[NL * 8 + c];
        out[(size_t)n * NC + c] = zc;
        out[(size_t)N * NC + (size_t)n * NC + c] = lacc;
    }
}

// ---------------- legacy monolithic kernel (ws-too-small fallback) ----------
extern "C" __global__ void __launch_bounds__(256)
flow_kernel(const float* __restrict__ x, const float* __restrict__ w,
            const float* __restrict__ h, const float* __restrict__ s,
            const float* __restrict__ bias, const float* __restrict__ lsc,
            float* __restrict__ out, int N)
{
    __shared__ float T[PT_FLOATS];
    __shared__ float Bb[NL + 1][NC];
    __shared__ float Sc[NL + 1][NC];
    __shared__ float LJC[NC];

    const int tid = threadIdx.x;
    if (tid < 64) {
        const int l = tid >> 3, c = tid & 7;
        float* cw = &T[tid * 99];
        {
            const float* wr = w + (l * NC + c) * NB;
            float m = wr[0];
            for (int b = 1; b < NB; ++b) m = fmaxf(m, wr[b]);
            float sum = 0.f;
            for (int b = 0; b < NB; ++b) sum += expf(wr[b] - m);
            float inv = 1.f / sum;
            float acc = 0.f;
            cw[0] = -TB;
            for (int b = 0; b < NB; ++b) {
                acc += 1e-3f + (1.f - 1e-3f * NB) * (expf(wr[b] - m) * inv);
                cw[b + 1] = 6.f * acc - 3.f;
            }
            cw[NB] = TB;
        }
        {
            float* ch = cw + 33;
            const float* hr = h + (l * NC + c) * NB;
            float m = hr[0];
            for (int b = 1; b < NB; ++b) m = fmaxf(m, hr[b]);
            float sum = 0.f;
            for (int b = 0; b < NB; ++b) sum += expf(hr[b] - m);
            float inv = 1.f / sum;
            float acc = 0.f;
            ch[0] = -TB;
            for (int b = 0; b < NB; ++b) {
                acc += 1e-3f + (1.f - 1e-3f * NB) * (expf(hr[b] - m) * inv);
                ch[b + 1] = 6.f * acc - 3.f;
            }
            ch[NB] = TB;
        }
        {
            float* dv = cw + 66;
            const float* sr = s + (l * NC + c) * (NB - 1);
            const float cst = logf(expm1f(1.f - 1e-3f));
            const float dbound = 1e-3f + softplusf(cst);
            dv[0]  = dbound;
            dv[NB] = dbound;
            for (int k = 0; k < NB - 1; ++k)
                dv[k + 1] = 1e-3f + softplusf(sr[k]);
        }
    }
    if (tid < (NL + 1) * NC) {
        const int l = tid >> 3, c = tid & 7;
        Bb[l][c] = bias[tid];
        Sc[l][c] = expf(-lsc[tid]);
    }
    if (tid < NC) {
        float a = 0.f;
        for (int l = 0; l <= NL; ++l) a += lsc[l * NC + tid];
        LJC[tid] = -a;
    }
    __syncthreads();

    const int n = blockIdx.x * 256 + tid;
    if (n >= N) return;
    const float xv = x[n];
    float z[NC], lj[NC];
#pragma unroll
    for (int c = 0; c < NC; ++c) { z[c] = xv; lj[c] = LJC[c]; }
#pragma unroll 1
    for (int l = 0; l < NL; ++l) {
        const float* Tl = &T[l * NC * 99];
#pragma unroll
        for (int c = 0; c < NC; ++c) {
            float zc = (z[c] - Bb[l][c]) * Sc[l][c];
            float zo, ld;
            spline_eval(Tl + c * 99, zc, zo, ld);
            z[c] = zo;
            lj[c] += ld;
        }
    }
#pragma unroll
    for (int c = 0; c < NC; ++c) z[c] = (z[c] - Bb[NL][c]) * Sc[NL][c];

    float4* oz = (float4*)(out + (size_t)n * NC);
    oz[0] = make_float4(z[0], z[1], z[2], z[3]);
    oz[1] = make_float4(z[4], z[5], z[6], z[7]);
    float4* ol = (float4*)(out + (size_t)N * NC + (size_t)n * NC);
    ol[0] = make_float4(lj[0], lj[1], lj[2], lj[3]);
    ol[1] = make_float4(lj[4], lj[5], lj[6], lj[7]);
}

extern "C" void kernel_launch(void* const* d_in, const int* in_sizes, int n_in,
                              void* d_out, int out_size, void* d_ws, size_t ws_size,
                              hipStream_t stream) {
    const float* x    = (const float*)d_in[0];
    const float* w    = (const float*)d_in[1];
    const float* h    = (const float*)d_in[2];
    const float* s    = (const float*)d_in[3];
    const float* bias = (const float*)d_in[4];
    const float* lsc  = (const float*)d_in[5];
    float* out = (float*)d_out;
    const int N = in_sizes[0];

    // Layout (bytes): [0,GP_BYTES) gparam | [SLOT_OFF,+8192) slotidx |
    //   [CNT_OFF,+16) cnt | [TAB_OFF,+G*64) packed tab | [..,end) worklist
    const int minWL = 8192;
    int G = 32768;   // absmax is G-insensitive (2.27@16K..2.09@128K); 2MB table = L2-resident
    while (G > 2048 &&
           ((size_t)TAB_OFF + (size_t)G * 64 + (size_t)minWL * 4) > ws_size)
        G >>= 1;
    const size_t tabEnd = (size_t)TAB_OFF + (size_t)G * 64;
    const size_t need   = tabEnd + (size_t)minWL * 4;

    if (need <= ws_size) {
        char* basep = (char*)d_ws;
        float*         gparam = (float*)basep;
        unsigned char* gsidx  = (unsigned char*)(basep + SLOT_OFF);
        unsigned*      cnt    = (unsigned*)(basep + CNT_OFF);
        char*          tabb   = basep + TAB_OFF;
        unsigned*      wl     = (unsigned*)(basep + tabEnd);
        long long capll = (long long)((ws_size - tabEnd) / 4);
        int wlcap = (int)((capll > N) ? N : capll);

        const float dx = (GX1 - GX0) / (float)(G - 1);
        const int nwaves  = (G - 1 + 6) / 7;          // 7 rows written per wave
        const int gblocks = (nwaves * 64 + 255) / 256;
        build_tables<<<1, 256, 0, stream>>>(w, h, s, bias, lsc, gparam, gsidx, cnt);
        grid_eval<<<gblocks, 256, 0, stream>>>(gparam, gsidx, tabb, G, dx);
        interp_kernel<<<(N + 255) / 256, 256, 0, stream>>>(
            x, tabb, gparam, out, cnt, wl, wlcap, N, G, dx, 1.f / dx);
        exact_kernel<<<256, 256, 0, stream>>>(x, gparam, cnt, wl, wlcap, out, N);
    } else {
        flow_kernel<<<(N + 255) / 256, 256, 0, stream>>>(
            x, w, h, s, bias, lsc, out, N);
    }
}

// Round 11
// 74.975 us; speedup vs baseline: 2.0716x; 2.0716x over previous
//
#include <hip/hip_runtime.h>
#include <hip/hip_bf16.h>

// UnivariateFlowMixture: N=1e6 points, C=8 channels, L=8 layers, B=32 bins.
// Pipeline: build_tables (1 blk) -> grid_eval (1 thread per grid point,
// r1-style 8ch serial eval, LDS f16 neighbor exchange, packed 64B rows) ->
// interp (1-line lerp, per-wave private worklist regions, ZERO atomics) ->
// exact (one wave per source-wave region).
// Round 11: r10's 108us interp @G=32768 = atomic serialization on one cnt
// line (VALU 2.4%, occ 64%, 650GB/s). Fix: private per-wave wl regions.
// G back to 131072 (fast-interp regime, absmax 2.09).

#define TB 3.0f
#define NB 32
#define NC 8
#define NL 8
#define LN2 0.69314718055994530942f

#define GX0 -6.5f
#define GX1 6.5f
#define TZ 0.5f
#define TL 0.5f

#define PT_FLOATS (64 * 99)                  // 6336: 64 tables of 33|33|33
#define GP_FLOATS (PT_FLOATS + 72 + 72 + 8)  // + Sc | Bb | LJ  (6488 floats)
#define GP_BYTES  (GP_FLOATS * 4)            // 25952
#define TAB_OFF   26112                      // 64B-aligned (64*408)

__device__ __forceinline__ float softplusf(float v) {
    return fmaxf(v, 0.f) + log1pf(expf(-fabsf(v)));
}

__device__ __forceinline__ unsigned short f2h(float f) {
    _Float16 h = (_Float16)f;
    unsigned short u;
    __builtin_memcpy(&u, &h, 2);
    return u;
}
__device__ __forceinline__ float h2f(unsigned short u) {
    _Float16 h;
    __builtin_memcpy(&h, &u, 2);
    return (float)h;
}

__device__ __forceinline__ int bsearch32(const float* __restrict__ E, float xc) {
    int i = (xc >= E[16]) ? 16 : 0;
    i += (xc >= E[i + 8]) ? 8 : 0;
    i += (xc >= E[i + 4]) ? 4 : 0;
    i += (xc >= E[i + 2]) ? 2 : 0;
    i += (xc >= E[i + 1]) ? 1 : 0;
    return i;
}

// Tlc: [0..32] cumw edges, [33..65] cumh, [66..98] derivs (LDS or global)
__device__ __forceinline__ void spline_eval(const float* __restrict__ Tlc,
                                            float zc, float& zo, float& ldo) {
    const float* E  = Tlc;
    const float* Hc = Tlc + 33;
    const float* Dv = Tlc + 66;

    float xc = fminf(fmaxf(zc, -TB), TB);
    int i = bsearch32(E, xc);

    float xk  = E[i],  xk1 = E[i + 1];
    float yk  = Hc[i], yk1 = Hc[i + 1];
    float dk  = Dv[i], dk1 = Dv[i + 1];

    float wk    = xk1 - xk;
    float hk    = yk1 - yk;
    float invw  = __builtin_amdgcn_rcpf(wk);
    float delta = hk * invw;
    float th    = (xc - xk) * invw;
    float omt   = 1.f - th;
    float t1m   = th * omt;
    float th2   = th * th;

    float num    = hk * fmaf(delta, th2, dk * t1m);
    float den    = fmaf(fmaf(-2.f, delta, dk + dk1), t1m, delta);
    float invden = __builtin_amdgcn_rcpf(den);
    float y      = fmaf(num, invden, yk);

    float dt    = delta * t1m;
    float inner = fmaf(dk1, th2, fmaf(dk, omt * omt, dt + dt));
    float dnum  = (delta * delta) * inner;
    float r  = dnum * invden * invden;
    float ld = LN2 * __builtin_amdgcn_logf(r);

    bool inside = (zc >= -TB) && (zc <= TB);
    zo  = inside ? y : zc;
    ldo = inside ? ld : 0.f;
}

// ---------------- kernel 1: build tables once -> gparam ----------------
extern "C" __global__ void __launch_bounds__(256)
build_tables(const float* __restrict__ w, const float* __restrict__ h,
             const float* __restrict__ s, const float* __restrict__ bias,
             const float* __restrict__ lsc, float* __restrict__ gparam)
{
    __shared__ float T[PT_FLOATS];
    __shared__ float Sc[72], Bb[72], LJ[8];

    const int tid = threadIdx.x;

    if (tid < 64) {                       // widths -> cumw edges
        const int l = tid >> 3, c = tid & 7;
        float* cw = &T[tid * 99];
        const float* wr = w + (l * NC + c) * NB;
        float m = wr[0];
        for (int b = 1; b < NB; ++b) m = fmaxf(m, wr[b]);
        float sum = 0.f;
        for (int b = 0; b < NB; ++b) sum += expf(wr[b] - m);
        float inv = 1.f / sum;
        float acc = 0.f;
        cw[0] = -TB;
        for (int b = 0; b < NB; ++b) {
            acc += 1e-3f + (1.f - 1e-3f * NB) * (expf(wr[b] - m) * inv);
            cw[b + 1] = 6.f * acc - 3.f;
        }
        cw[NB] = TB;
    } else if (tid < 128) {               // heights -> cumh
        const int t = tid - 64;
        float* ch = &T[t * 99 + 33];
        const int l = t >> 3, c = t & 7;
        const float* hr = h + (l * NC + c) * NB;
        float m = hr[0];
        for (int b = 1; b < NB; ++b) m = fmaxf(m, hr[b]);
        float sum = 0.f;
        for (int b = 0; b < NB; ++b) sum += expf(hr[b] - m);
        float inv = 1.f / sum;
        float acc = 0.f;
        ch[0] = -TB;
        for (int b = 0; b < NB; ++b) {
            acc += 1e-3f + (1.f - 1e-3f * NB) * (expf(hr[b] - m) * inv);
            ch[b + 1] = 6.f * acc - 3.f;
        }
        ch[NB] = TB;
    } else if (tid < 192) {               // derivs
        const int t = tid - 128;
        const int l = t >> 3, c = t & 7;
        float* dv = &T[t * 99 + 66];
        const float* sr = s + (l * NC + c) * (NB - 1);
        const float cst = logf(expm1f(1.f - 1e-3f));
        const float dbound = 1e-3f + softplusf(cst);
        dv[0]  = dbound;
        dv[NB] = dbound;
        for (int k = 0; k < NB - 1; ++k)
            dv[k + 1] = 1e-3f + softplusf(sr[k]);
    }
    if (tid < 72) { Sc[tid] = expf(-lsc[tid]); Bb[tid] = bias[tid]; }
    if (tid < 8) {
        float a = 0.f;
        for (int l = 0; l <= NL; ++l) a += lsc[l * NC + tid];
        LJ[tid] = -a;
    }
    __syncthreads();

    for (int k = tid; k < PT_FLOATS; k += 256) gparam[k] = T[k];
    if (tid < 72) gparam[PT_FLOATS + tid]       = Sc[tid];
    if (tid < 72) gparam[PT_FLOATS + 72 + tid]  = Bb[tid];
    if (tid < 8)  gparam[PT_FLOATS + 144 + tid] = LJ[tid];
}

// ------- kernel 2: grid eval, 1 thread per grid point (8 ch serial) --------
// Block covers 256 points with 1 overlap: rows [b*255, b*255+254] written.
// Neighbor exchange via f16-packed LDS (8 KB). Row i at tabb+i*64:
// per channel c at byte c*8: {h(z_i), h(dz), h(lj_i), h(dlj)}
extern "C" __global__ void __launch_bounds__(256)
grid_eval(const float* __restrict__ gparam, char* __restrict__ tabb,
          int G, float dx)
{
    __shared__ float T[GP_FLOATS];
    __shared__ unsigned short ZL[256 * 16];   // h(z)[8] | h(lj)[8] per thread
    for (int k = threadIdx.x; k < GP_FLOATS; k += 256) T[k] = gparam[k];
    __syncthreads();
    const float* ScT = T + PT_FLOATS;
    const float* BbT = ScT + 72;
    const float* LJT = BbT + 72;

    const int t  = threadIdx.x;
    const int p0 = blockIdx.x * 255;
    const int i  = min(p0 + t, G - 1);

    const float xv = fmaf((float)i, dx, GX0);
    float z[NC], lj[NC];
#pragma unroll
    for (int c = 0; c < NC; ++c) { z[c] = xv; lj[c] = LJT[c]; }

#pragma unroll 1
    for (int l = 0; l < NL; ++l) {
        const float* Tl = T + l * NC * 99;
#pragma unroll
        for (int c = 0; c < NC; ++c) {
            float u = (z[c] - BbT[l * 8 + c]) * ScT[l * 8 + c];
            float zo, ld;
            spline_eval(Tl + c * 99, u, zo, ld);
            z[c] = zo;
            lj[c] += ld;
        }
    }
    unsigned short zh[NC], lh[NC];
#pragma unroll
    for (int c = 0; c < NC; ++c) {
        z[c] = (z[c] - BbT[NL * 8 + c]) * ScT[NL * 8 + c];
        zh[c] = f2h(z[c]);
        lh[c] = f2h(lj[c]);
        ZL[t * 16 + c]     = zh[c];
        ZL[t * 16 + 8 + c] = lh[c];
    }
    __syncthreads();

    const int r = p0 + t;
    if (t < 255 && r <= G - 2) {
        ushort4* rowp = (ushort4*)(tabb + (size_t)r * 64);
#pragma unroll
        for (int c = 0; c < NC; ++c) {
            const float zn  = h2f(ZL[(t + 1) * 16 + c]);
            const float ljn = h2f(ZL[(t + 1) * 16 + 8 + c]);
            ushort4 v;
            v.x = zh[c]; v.y = f2h(zn - h2f(zh[c]));
            v.z = lh[c]; v.w = f2h(ljn - h2f(lh[c]));
            rowp[c] = v;
        }
    }
}

// ------- kernel 3: interpolate; private per-wave worklist (no atomics) ------
extern "C" __global__ void __launch_bounds__(256)
interp_kernel(const float* __restrict__ x, const char* __restrict__ tabb,
              float* __restrict__ out,
              unsigned* __restrict__ wcnt, unsigned* __restrict__ wl,
              int N, int G, float dx, float invdx)
{
    const int n   = blockIdx.x * 256 + threadIdx.x;
    const int wid = n >> 6;
    if (n >= N) return;

    const float xv = x[n];
    int i = (int)floorf((xv - GX0) * invdx);
    const bool oor = !(xv > GX0 && xv < GX1);
    i = min(max(i, 0), G - 2);
    const float t = (xv - fmaf((float)i, dx, GX0)) * invdx;

    const float4* rp = (const float4*)(tabb + (size_t)i * 64);
    union { float4 q[4]; unsigned int u[16]; } R;
    R.q[0] = rp[0]; R.q[1] = rp[1]; R.q[2] = rp[2]; R.q[3] = rp[3];

    float z[NC], lj[NC];
    int flags = 0;
#pragma unroll
    for (int c = 0; c < NC; ++c) {
        const unsigned a = R.u[2 * c], b = R.u[2 * c + 1];
        const float z0 = h2f((unsigned short)a);
        const float dz = h2f((unsigned short)(a >> 16));
        const float l0 = h2f((unsigned short)b);
        const float dl = h2f((unsigned short)(b >> 16));
        z[c]  = fmaf(t, dz, z0);
        lj[c] = fmaf(t, dl, l0);
        if (fabsf(dz) > TZ || fabsf(dl) > TL) flags |= (1 << c);
    }
    if (oor) flags = 0xff;

    // private region compaction: no atomics anywhere
    const unsigned long long act = __ballot(1);
    const unsigned long long m   = __ballot(flags != 0);
    const int lane = threadIdx.x & 63;
    if (flags) {
        const int rank = __popcll(m & ((1ull << lane) - 1ull));
        wl[(size_t)wid * 64 + rank] = ((unsigned)n << 8) | (unsigned)flags;
    }
    if (lane == __ffsll((long long)act) - 1)
        wcnt[wid] = (unsigned)__popcll(m);

    float4* oz = (float4*)(out + (size_t)n * NC);
    oz[0] = make_float4(z[0], z[1], z[2], z[3]);
    oz[1] = make_float4(z[4], z[5], z[6], z[7]);
    float4* ol = (float4*)(out + (size_t)N * NC + (size_t)n * NC);
    ol[0] = make_float4(lj[0], lj[1], lj[2], lj[3]);
    ol[1] = make_float4(lj[4], lj[5], lj[6], lj[7]);
}

// ------- kernel 4: exact pass, one wave per source-wave region --------------
extern "C" __global__ void __launch_bounds__(256)
exact_kernel(const float* __restrict__ x, const float* __restrict__ gparam,
             const unsigned* __restrict__ wcnt, const unsigned* __restrict__ wl,
             int nwl, float* __restrict__ out, int N)
{
    __shared__ float T[GP_FLOATS];
    for (int k = threadIdx.x; k < GP_FLOATS; k += 256) T[k] = gparam[k];
    __syncthreads();
    const float* ScT = T + PT_FLOATS;
    const float* BbT = ScT + 72;
    const float* LJT = BbT + 72;

    const int lane = threadIdx.x & 63;
    const int wloc = threadIdx.x >> 6;    // 0..3
    for (int W = blockIdx.x * 4 + wloc; W < nwl; W += (int)gridDim.x * 4) {
        const unsigned cnt = min(wcnt[W], 64u);
        for (unsigned p = 0; p < cnt; p += 8) {
            const unsigned eidx = p + (unsigned)(lane >> 3);
            if (eidx >= cnt) continue;
            const unsigned ent = wl[(size_t)W * 64 + eidx];
            const int c = lane & 7;
            if (!((ent >> c) & 1u)) continue;
            const int n = (int)(ent >> 8);
            if (n >= N) continue;         // defensive
            const float xv = x[n];
            float zc = xv;
            float lacc = LJT[c];
#pragma unroll 1
            for (int l = 0; l < NL; ++l) {
                zc = (zc - BbT[l * 8 + c]) * ScT[l * 8 + c];
                float ld;
                spline_eval(T + (l * 8 + c) * 99, zc, zc, ld);
                lacc += ld;
            }
            zc = (zc - BbT[NL * 8 + c]) * ScT[NL * 8 + c];
            out[(size_t)n * NC + c] = zc;
            out[(size_t)N * NC + (size_t)n * NC + c] = lacc;
        }
    }
}

// ---------------- legacy monolithic kernel (ws-too-small fallback) ----------
extern "C" __global__ void __launch_bounds__(256)
flow_kernel(const float* __restrict__ x, const float* __restrict__ w,
            const float* __restrict__ h, const float* __restrict__ s,
            const float* __restrict__ bias, const float* __restrict__ lsc,
            float* __restrict__ out, int N)
{
    __shared__ float T[PT_FLOATS];
    __shared__ float Bb[NL + 1][NC];
    __shared__ float Sc[NL + 1][NC];
    __shared__ float LJC[NC];

    const int tid = threadIdx.x;
    if (tid < 64) {
        const int l = tid >> 3, c = tid & 7;
        float* cw = &T[tid * 99];
        {
            const float* wr = w + (l * NC + c) * NB;
            float m = wr[0];
            for (int b = 1; b < NB; ++b) m = fmaxf(m, wr[b]);
            float sum = 0.f;
            for (int b = 0; b < NB; ++b) sum += expf(wr[b] - m);
            float inv = 1.f / sum;
            float acc = 0.f;
            cw[0] = -TB;
            for (int b = 0; b < NB; ++b) {
                acc += 1e-3f + (1.f - 1e-3f * NB) * (expf(wr[b] - m) * inv);
                cw[b + 1] = 6.f * acc - 3.f;
            }
            cw[NB] = TB;
        }
        {
            float* ch = cw + 33;
            const float* hr = h + (l * NC + c) * NB;
            float m = hr[0];
            for (int b = 1; b < NB; ++b) m = fmaxf(m, hr[b]);
            float sum = 0.f;
            for (int b = 0; b < NB; ++b) sum += expf(hr[b] - m);
            float inv = 1.f / sum;
            float acc = 0.f;
            ch[0] = -TB;
            for (int b = 0; b < NB; ++b) {
                acc += 1e-3f + (1.f - 1e-3f * NB) * (expf(hr[b] - m) * inv);
                ch[b + 1] = 6.f * acc - 3.f;
            }
            ch[NB] = TB;
        }
        {
            float* dv = cw + 66;
            const float* sr = s + (l * NC + c) * (NB - 1);
            const float cst = logf(expm1f(1.f - 1e-3f));
            const float dbound = 1e-3f + softplusf(cst);
            dv[0]  = dbound;
            dv[NB] = dbound;
            for (int k = 0; k < NB - 1; ++k)
                dv[k + 1] = 1e-3f + softplusf(sr[k]);
        }
    }
    if (tid < (NL + 1) * NC) {
        const int l = tid >> 3, c = tid & 7;
        Bb[l][c] = bias[tid];
        Sc[l][c] = expf(-lsc[tid]);
    }
    if (tid < NC) {
        float a = 0.f;
        for (int l = 0; l <= NL; ++l) a += lsc[l * NC + tid];
        LJC[tid] = -a;
    }
    __syncthreads();

    const int n = blockIdx.x * 256 + tid;
    if (n >= N) return;
    const float xv = x[n];
    float z[NC], lj[NC];
#pragma unroll
    for (int c = 0; c < NC; ++c) { z[c] = xv; lj[c] = LJC[c]; }
#pragma unroll 1
    for (int l = 0; l < NL; ++l) {
        const float* Tl = &T[l * NC * 99];
#pragma unroll
        for (int c = 0; c < NC; ++c) {
            float zc = (z[c] - Bb[l][c]) * Sc[l][c];
            float zo, ld;
            spline_eval(Tl + c * 99, zc, zo, ld);
            z[c] = zo;
            lj[c] += ld;
        }
    }
#pragma unroll
    for (int c = 0; c < NC; ++c) z[c] = (z[c] - Bb[NL][c]) * Sc[NL][c];

    float4* oz = (float4*)(out + (size_t)n * NC);
    oz[0] = make_float4(z[0], z[1], z[2], z[3]);
    oz[1] = make_float4(z[4], z[5], z[6], z[7]);
    float4* ol = (float4*)(out + (size_t)N * NC + (size_t)n * NC);
    ol[0] = make_float4(lj[0], lj[1], lj[2], lj[3]);
    ol[1] = make_float4(lj[4], lj[5], lj[6], lj[7]);
}

extern "C" void kernel_launch(void* const* d_in, const int* in_sizes, int n_in,
                              void* d_out, int out_size, void* d_ws, size_t ws_size,
                              hipStream_t stream) {
    const float* x    = (const float*)d_in[0];
    const float* w    = (const float*)d_in[1];
    const float* h    = (const float*)d_in[2];
    const float* s    = (const float*)d_in[3];
    const float* bias = (const float*)d_in[4];
    const float* lsc  = (const float*)d_in[5];
    float* out = (float*)d_out;
    const int N = in_sizes[0];

    const int nwl = (N + 63) / 64;        // per-wave worklist regions
    // Layout (bytes): [0,GP_BYTES) gparam | [TAB_OFF,+G*64) packed tab |
    //   [tabEnd,+nwl*4) wcnt | [.., +nwl*256) wl
    int G = 131072;
    while (G > 2048 &&
           ((size_t)TAB_OFF + (size_t)G * 64 + (size_t)nwl * 260) > ws_size)
        G >>= 1;
    const size_t tabEnd = (size_t)TAB_OFF + (size_t)G * 64;
    const size_t need   = tabEnd + (size_t)nwl * 260;

    if (need <= ws_size) {
        char* basep = (char*)d_ws;
        float*    gparam = (float*)basep;
        char*     tabb   = basep + TAB_OFF;
        unsigned* wcnt   = (unsigned*)(basep + tabEnd);
        unsigned* wl     = (unsigned*)(basep + tabEnd + (size_t)nwl * 4);

        const float dx = (GX1 - GX0) / (float)(G - 1);
        const int gblocks = (G - 1 + 254) / 255;
        build_tables<<<1, 256, 0, stream>>>(w, h, s, bias, lsc, gparam);
        grid_eval<<<gblocks, 256, 0, stream>>>(gparam, tabb, G, dx);
        interp_kernel<<<(N + 255) / 256, 256, 0, stream>>>(
            x, tabb, out, wcnt, wl, N, G, dx, 1.f / dx);
        exact_kernel<<<(nwl + 3) / 4, 256, 0, stream>>>(
            x, gparam, wcnt, wl, nwl, out, N);
    } else {
        flow_kernel<<<(N + 255) / 256, 256, 0, stream>>>(
            x, w, h, s, bias, lsc, out, N);
    }
}

// Round 12
// 70.905 us; speedup vs baseline: 2.1905x; 1.0574x over previous
//
#include <hip/hip_runtime.h>
#include <hip/hip_bf16.h>

// UnivariateFlowMixture: N=1e6 points, C=8 channels, L=8 layers, B=32 bins.
// Pipeline: build_tables (1 blk) -> grid_eval (1 thread per grid point,
// r1-style 8ch serial eval, LDS f16 neighbor exchange, packed 64B rows) ->
// interp (1-line lerp, per-wave private worklist regions, ZERO atomics) ->
// exact (one wave per source-wave region).
// Round 12: G=65536. grid_eval cost ~G (halves); interp hot region ~1.8MB
// -> fits one XCD L2 (at 131072 it was ~3.7MB, borderline). Flag rate 2x is
// harmless now (no atomics; exact is per entry-channel parallel).

#define TB 3.0f
#define NB 32
#define NC 8
#define NL 8
#define LN2 0.69314718055994530942f

#define GX0 -6.5f
#define GX1 6.5f
#define TZ 0.5f
#define TL 0.5f

#define PT_FLOATS (64 * 99)                  // 6336: 64 tables of 33|33|33
#define GP_FLOATS (PT_FLOATS + 72 + 72 + 8)  // + Sc | Bb | LJ  (6488 floats)
#define GP_BYTES  (GP_FLOATS * 4)            // 25952
#define TAB_OFF   26112                      // 64B-aligned (64*408)

__device__ __forceinline__ float softplusf(float v) {
    return fmaxf(v, 0.f) + log1pf(expf(-fabsf(v)));
}

__device__ __forceinline__ unsigned short f2h(float f) {
    _Float16 h = (_Float16)f;
    unsigned short u;
    __builtin_memcpy(&u, &h, 2);
    return u;
}
__device__ __forceinline__ float h2f(unsigned short u) {
    _Float16 h;
    __builtin_memcpy(&h, &u, 2);
    return (float)h;
}

__device__ __forceinline__ int bsearch32(const float* __restrict__ E, float xc) {
    int i = (xc >= E[16]) ? 16 : 0;
    i += (xc >= E[i + 8]) ? 8 : 0;
    i += (xc >= E[i + 4]) ? 4 : 0;
    i += (xc >= E[i + 2]) ? 2 : 0;
    i += (xc >= E[i + 1]) ? 1 : 0;
    return i;
}

// Tlc: [0..32] cumw edges, [33..65] cumh, [66..98] derivs (LDS or global)
__device__ __forceinline__ void spline_eval(const float* __restrict__ Tlc,
                                            float zc, float& zo, float& ldo) {
    const float* E  = Tlc;
    const float* Hc = Tlc + 33;
    const float* Dv = Tlc + 66;

    float xc = fminf(fmaxf(zc, -TB), TB);
    int i = bsearch32(E, xc);

    float xk  = E[i],  xk1 = E[i + 1];
    float yk  = Hc[i], yk1 = Hc[i + 1];
    float dk  = Dv[i], dk1 = Dv[i + 1];

    float wk    = xk1 - xk;
    float hk    = yk1 - yk;
    float invw  = __builtin_amdgcn_rcpf(wk);
    float delta = hk * invw;
    float th    = (xc - xk) * invw;
    float omt   = 1.f - th;
    float t1m   = th * omt;
    float th2   = th * th;

    float num    = hk * fmaf(delta, th2, dk * t1m);
    float den    = fmaf(fmaf(-2.f, delta, dk + dk1), t1m, delta);
    float invden = __builtin_amdgcn_rcpf(den);
    float y      = fmaf(num, invden, yk);

    float dt    = delta * t1m;
    float inner = fmaf(dk1, th2, fmaf(dk, omt * omt, dt + dt));
    float dnum  = (delta * delta) * inner;
    float r  = dnum * invden * invden;
    float ld = LN2 * __builtin_amdgcn_logf(r);

    bool inside = (zc >= -TB) && (zc <= TB);
    zo  = inside ? y : zc;
    ldo = inside ? ld : 0.f;
}

// ---------------- kernel 1: build tables once -> gparam ----------------
extern "C" __global__ void __launch_bounds__(256)
build_tables(const float* __restrict__ w, const float* __restrict__ h,
             const float* __restrict__ s, const float* __restrict__ bias,
             const float* __restrict__ lsc, float* __restrict__ gparam)
{
    __shared__ float T[PT_FLOATS];
    __shared__ float Sc[72], Bb[72], LJ[8];

    const int tid = threadIdx.x;

    if (tid < 64) {                       // widths -> cumw edges
        const int l = tid >> 3, c = tid & 7;
        float* cw = &T[tid * 99];
        const float* wr = w + (l * NC + c) * NB;
        float m = wr[0];
        for (int b = 1; b < NB; ++b) m = fmaxf(m, wr[b]);
        float sum = 0.f;
        for (int b = 0; b < NB; ++b) sum += expf(wr[b] - m);
        float inv = 1.f / sum;
        float acc = 0.f;
        cw[0] = -TB;
        for (int b = 0; b < NB; ++b) {
            acc += 1e-3f + (1.f - 1e-3f * NB) * (expf(wr[b] - m) * inv);
            cw[b + 1] = 6.f * acc - 3.f;
        }
        cw[NB] = TB;
    } else if (tid < 128) {               // heights -> cumh
        const int t = tid - 64;
        float* ch = &T[t * 99 + 33];
        const int l = t >> 3, c = t & 7;
        const float* hr = h + (l * NC + c) * NB;
        float m = hr[0];
        for (int b = 1; b < NB; ++b) m = fmaxf(m, hr[b]);
        float sum = 0.f;
        for (int b = 0; b < NB; ++b) sum += expf(hr[b] - m);
        float inv = 1.f / sum;
        float acc = 0.f;
        ch[0] = -TB;
        for (int b = 0; b < NB; ++b) {
            acc += 1e-3f + (1.f - 1e-3f * NB) * (expf(hr[b] - m) * inv);
            ch[b + 1] = 6.f * acc - 3.f;
        }
        ch[NB] = TB;
    } else if (tid < 192) {               // derivs
        const int t = tid - 128;
        const int l = t >> 3, c = t & 7;
        float* dv = &T[t * 99 + 66];
        const float* sr = s + (l * NC + c) * (NB - 1);
        const float cst = logf(expm1f(1.f - 1e-3f));
        const float dbound = 1e-3f + softplusf(cst);
        dv[0]  = dbound;
        dv[NB] = dbound;
        for (int k = 0; k < NB - 1; ++k)
            dv[k + 1] = 1e-3f + softplusf(sr[k]);
    }
    if (tid < 72) { Sc[tid] = expf(-lsc[tid]); Bb[tid] = bias[tid]; }
    if (tid < 8) {
        float a = 0.f;
        for (int l = 0; l <= NL; ++l) a += lsc[l * NC + tid];
        LJ[tid] = -a;
    }
    __syncthreads();

    for (int k = tid; k < PT_FLOATS; k += 256) gparam[k] = T[k];
    if (tid < 72) gparam[PT_FLOATS + tid]       = Sc[tid];
    if (tid < 72) gparam[PT_FLOATS + 72 + tid]  = Bb[tid];
    if (tid < 8)  gparam[PT_FLOATS + 144 + tid] = LJ[tid];
}

// ------- kernel 2: grid eval, 1 thread per grid point (8 ch serial) --------
// Block covers 256 points with 1 overlap: rows [b*255, b*255+254] written.
// Neighbor exchange via f16-packed LDS (8 KB). Row i at tabb+i*64:
// per channel c at byte c*8: {h(z_i), h(dz), h(lj_i), h(dlj)}
extern "C" __global__ void __launch_bounds__(256)
grid_eval(const float* __restrict__ gparam, char* __restrict__ tabb,
          int G, float dx)
{
    __shared__ float T[GP_FLOATS];
    __shared__ unsigned short ZL[256 * 16];   // h(z)[8] | h(lj)[8] per thread
    for (int k = threadIdx.x; k < GP_FLOATS; k += 256) T[k] = gparam[k];
    __syncthreads();
    const float* ScT = T + PT_FLOATS;
    const float* BbT = ScT + 72;
    const float* LJT = BbT + 72;

    const int t  = threadIdx.x;
    const int p0 = blockIdx.x * 255;
    const int i  = min(p0 + t, G - 1);

    const float xv = fmaf((float)i, dx, GX0);
    float z[NC], lj[NC];
#pragma unroll
    for (int c = 0; c < NC; ++c) { z[c] = xv; lj[c] = LJT[c]; }

#pragma unroll 1
    for (int l = 0; l < NL; ++l) {
        const float* Tl = T + l * NC * 99;
#pragma unroll
        for (int c = 0; c < NC; ++c) {
            float u = (z[c] - BbT[l * 8 + c]) * ScT[l * 8 + c];
            float zo, ld;
            spline_eval(Tl + c * 99, u, zo, ld);
            z[c] = zo;
            lj[c] += ld;
        }
    }
    unsigned short zh[NC], lh[NC];
#pragma unroll
    for (int c = 0; c < NC; ++c) {
        z[c] = (z[c] - BbT[NL * 8 + c]) * ScT[NL * 8 + c];
        zh[c] = f2h(z[c]);
        lh[c] = f2h(lj[c]);
        ZL[t * 16 + c]     = zh[c];
        ZL[t * 16 + 8 + c] = lh[c];
    }
    __syncthreads();

    const int r = p0 + t;
    if (t < 255 && r <= G - 2) {
        ushort4* rowp = (ushort4*)(tabb + (size_t)r * 64);
#pragma unroll
        for (int c = 0; c < NC; ++c) {
            const float zn  = h2f(ZL[(t + 1) * 16 + c]);
            const float ljn = h2f(ZL[(t + 1) * 16 + 8 + c]);
            ushort4 v;
            v.x = zh[c]; v.y = f2h(zn - h2f(zh[c]));
            v.z = lh[c]; v.w = f2h(ljn - h2f(lh[c]));
            rowp[c] = v;
        }
    }
}

// ------- kernel 3: interpolate; private per-wave worklist (no atomics) ------
extern "C" __global__ void __launch_bounds__(256)
interp_kernel(const float* __restrict__ x, const char* __restrict__ tabb,
              float* __restrict__ out,
              unsigned* __restrict__ wcnt, unsigned* __restrict__ wl,
              int N, int G, float dx, float invdx)
{
    const int n   = blockIdx.x * 256 + threadIdx.x;
    const int wid = n >> 6;
    if (n >= N) return;

    const float xv = x[n];
    int i = (int)floorf((xv - GX0) * invdx);
    const bool oor = !(xv > GX0 && xv < GX1);
    i = min(max(i, 0), G - 2);
    const float t = (xv - fmaf((float)i, dx, GX0)) * invdx;

    const float4* rp = (const float4*)(tabb + (size_t)i * 64);
    union { float4 q[4]; unsigned int u[16]; } R;
    R.q[0] = rp[0]; R.q[1] = rp[1]; R.q[2] = rp[2]; R.q[3] = rp[3];

    float z[NC], lj[NC];
    int flags = 0;
#pragma unroll
    for (int c = 0; c < NC; ++c) {
        const unsigned a = R.u[2 * c], b = R.u[2 * c + 1];
        const float z0 = h2f((unsigned short)a);
        const float dz = h2f((unsigned short)(a >> 16));
        const float l0 = h2f((unsigned short)b);
        const float dl = h2f((unsigned short)(b >> 16));
        z[c]  = fmaf(t, dz, z0);
        lj[c] = fmaf(t, dl, l0);
        if (fabsf(dz) > TZ || fabsf(dl) > TL) flags |= (1 << c);
    }
    if (oor) flags = 0xff;

    // private region compaction: no atomics anywhere
    const unsigned long long act = __ballot(1);
    const unsigned long long m   = __ballot(flags != 0);
    const int lane = threadIdx.x & 63;
    if (flags) {
        const int rank = __popcll(m & ((1ull << lane) - 1ull));
        wl[(size_t)wid * 64 + rank] = ((unsigned)n << 8) | (unsigned)flags;
    }
    if (lane == __ffsll((long long)act) - 1)
        wcnt[wid] = (unsigned)__popcll(m);

    float4* oz = (float4*)(out + (size_t)n * NC);
    oz[0] = make_float4(z[0], z[1], z[2], z[3]);
    oz[1] = make_float4(z[4], z[5], z[6], z[7]);
    float4* ol = (float4*)(out + (size_t)N * NC + (size_t)n * NC);
    ol[0] = make_float4(lj[0], lj[1], lj[2], lj[3]);
    ol[1] = make_float4(lj[4], lj[5], lj[6], lj[7]);
}

// ------- kernel 4: exact pass, one wave per source-wave region --------------
extern "C" __global__ void __launch_bounds__(256)
exact_kernel(const float* __restrict__ x, const float* __restrict__ gparam,
             const unsigned* __restrict__ wcnt, const unsigned* __restrict__ wl,
             int nwl, float* __restrict__ out, int N)
{
    __shared__ float T[GP_FLOATS];
    for (int k = threadIdx.x; k < GP_FLOATS; k += 256) T[k] = gparam[k];
    __syncthreads();
    const float* ScT = T + PT_FLOATS;
    const float* BbT = ScT + 72;
    const float* LJT = BbT + 72;

    const int lane = threadIdx.x & 63;
    const int wloc = threadIdx.x >> 6;    // 0..3
    for (int W = blockIdx.x * 4 + wloc; W < nwl; W += (int)gridDim.x * 4) {
        const unsigned cnt = min(wcnt[W], 64u);
        for (unsigned p = 0; p < cnt; p += 8) {
            const unsigned eidx = p + (unsigned)(lane >> 3);
            if (eidx >= cnt) continue;
            const unsigned ent = wl[(size_t)W * 64 + eidx];
            const int c = lane & 7;
            if (!((ent >> c) & 1u)) continue;
            const int n = (int)(ent >> 8);
            if (n >= N) continue;         // defensive
            const float xv = x[n];
            float zc = xv;
            float lacc = LJT[c];
#pragma unroll 1
            for (int l = 0; l < NL; ++l) {
                zc = (zc - BbT[l * 8 + c]) * ScT[l * 8 + c];
                float ld;
                spline_eval(T + (l * 8 + c) * 99, zc, zc, ld);
                lacc += ld;
            }
            zc = (zc - BbT[NL * 8 + c]) * ScT[NL * 8 + c];
            out[(size_t)n * NC + c] = zc;
            out[(size_t)N * NC + (size_t)n * NC + c] = lacc;
        }
    }
}

// ---------------- legacy monolithic kernel (ws-too-small fallback) ----------
extern "C" __global__ void __launch_bounds__(256)
flow_kernel(const float* __restrict__ x, const float* __restrict__ w,
            const float* __restrict__ h, const float* __restrict__ s,
            const float* __restrict__ bias, const float* __restrict__ lsc,
            float* __restrict__ out, int N)
{
    __shared__ float T[PT_FLOATS];
    __shared__ float Bb[NL + 1][NC];
    __shared__ float Sc[NL + 1][NC];
    __shared__ float LJC[NC];

    const int tid = threadIdx.x;
    if (tid < 64) {
        const int l = tid >> 3, c = tid & 7;
        float* cw = &T[tid * 99];
        {
            const float* wr = w + (l * NC + c) * NB;
            float m = wr[0];
            for (int b = 1; b < NB; ++b) m = fmaxf(m, wr[b]);
            float sum = 0.f;
            for (int b = 0; b < NB; ++b) sum += expf(wr[b] - m);
            float inv = 1.f / sum;
            float acc = 0.f;
            cw[0] = -TB;
            for (int b = 0; b < NB; ++b) {
                acc += 1e-3f + (1.f - 1e-3f * NB) * (expf(wr[b] - m) * inv);
                cw[b + 1] = 6.f * acc - 3.f;
            }
            cw[NB] = TB;
        }
        {
            float* ch = cw + 33;
            const float* hr = h + (l * NC + c) * NB;
            float m = hr[0];
            for (int b = 1; b < NB; ++b) m = fmaxf(m, hr[b]);
            float sum = 0.f;
            for (int b = 0; b < NB; ++b) sum += expf(hr[b] - m);
            float inv = 1.f / sum;
            float acc = 0.f;
            ch[0] = -TB;
            for (int b = 0; b < NB; ++b) {
                acc += 1e-3f + (1.f - 1e-3f * NB) * (expf(hr[b] - m) * inv);
                ch[b + 1] = 6.f * acc - 3.f;
            }
            ch[NB] = TB;
        }
        {
            float* dv = cw + 66;
            const float* sr = s + (l * NC + c) * (NB - 1);
            const float cst = logf(expm1f(1.f - 1e-3f));
            const float dbound = 1e-3f + softplusf(cst);
            dv[0]  = dbound;
            dv[NB] = dbound;
            for (int k = 0; k < NB - 1; ++k)
                dv[k + 1] = 1e-3f + softplusf(sr[k]);
        }
    }
    if (tid < (NL + 1) * NC) {
        const int l = tid >> 3, c = tid & 7;
        Bb[l][c] = bias[tid];
        Sc[l][c] = expf(-lsc[tid]);
    }
    if (tid < NC) {
        float a = 0.f;
        for (int l = 0; l <= NL; ++l) a += lsc[l * NC + tid];
        LJC[tid] = -a;
    }
    __syncthreads();

    const int n = blockIdx.x * 256 + tid;
    if (n >= N) return;
    const float xv = x[n];
    float z[NC], lj[NC];
#pragma unroll
    for (int c = 0; c < NC; ++c) { z[c] = xv; lj[c] = LJC[c]; }
#pragma unroll 1
    for (int l = 0; l < NL; ++l) {
        const float* Tl = &T[l * NC * 99];
#pragma unroll
        for (int c = 0; c < NC; ++c) {
            float zc = (z[c] - Bb[l][c]) * Sc[l][c];
            float zo, ld;
            spline_eval(Tl + c * 99, zc, zo, ld);
            z[c] = zo;
            lj[c] += ld;
        }
    }
#pragma unroll
    for (int c = 0; c < NC; ++c) z[c] = (z[c] - Bb[NL][c]) * Sc[NL][c];

    float4* oz = (float4*)(out + (size_t)n * NC);
    oz[0] = make_float4(z[0], z[1], z[2], z[3]);
    oz[1] = make_float4(z[4], z[5], z[6], z[7]);
    float4* ol = (float4*)(out + (size_t)N * NC + (size_t)n * NC);
    ol[0] = make_float4(lj[0], lj[1], lj[2], lj[3]);
    ol[1] = make_float4(lj[4], lj[5], lj[6], lj[7]);
}

extern "C" void kernel_launch(void* const* d_in, const int* in_sizes, int n_in,
                              void* d_out, int out_size, void* d_ws, size_t ws_size,
                              hipStream_t stream) {
    const float* x    = (const float*)d_in[0];
    const float* w    = (const float*)d_in[1];
    const float* h    = (const float*)d_in[2];
    const float* s    = (const float*)d_in[3];
    const float* bias = (const float*)d_in[4];
    const float* lsc  = (const float*)d_in[5];
    float* out = (float*)d_out;
    const int N = in_sizes[0];

    const int nwl = (N + 63) / 64;        // per-wave worklist regions
    // Layout (bytes): [0,GP_BYTES) gparam | [TAB_OFF,+G*64) packed tab |
    //   [tabEnd,+nwl*4) wcnt | [.., +nwl*256) wl
    int G = 65536;
    while (G > 2048 &&
           ((size_t)TAB_OFF + (size_t)G * 64 + (size_t)nwl * 260) > ws_size)
        G >>= 1;
    const size_t tabEnd = (size_t)TAB_OFF + (size_t)G * 64;
    const size_t need   = tabEnd + (size_t)nwl * 260;

    if (need <= ws_size) {
        char* basep = (char*)d_ws;
        float*    gparam = (float*)basep;
        char*     tabb   = basep + TAB_OFF;
        unsigned* wcnt   = (unsigned*)(basep + tabEnd);
        unsigned* wl     = (unsigned*)(basep + tabEnd + (size_t)nwl * 4);

        const float dx = (GX1 - GX0) / (float)(G - 1);
        const int gblocks = (G - 1 + 254) / 255;
        build_tables<<<1, 256, 0, stream>>>(w, h, s, bias, lsc, gparam);
        grid_eval<<<gblocks, 256, 0, stream>>>(gparam, tabb, G, dx);
        interp_kernel<<<(N + 255) / 256, 256, 0, stream>>>(
            x, tabb, out, wcnt, wl, N, G, dx, 1.f / dx);
        exact_kernel<<<(nwl + 3) / 4, 256, 0, stream>>>(
            x, gparam, wcnt, wl, nwl, out, N);
    } else {
        flow_kernel<<<(N + 255) / 256, 256, 0, stream>>>(
            x, w, h, s, bias, lsc, out, N);
    }
}

// Round 13
// 63.912 us; speedup vs baseline: 2.4302x; 1.1094x over previous
//
#include <hip/hip_runtime.h>
#include <hip/hip_bf16.h>

// UnivariateFlowMixture: N=1e6 points, C=8 channels, L=8 layers, B=32 bins.
// Pipeline: build_tables (1 blk) -> grid_eval (1 thread/grid point, LDS f16
// neighbor exchange, packed 64B rows) -> interp_fused (lerp + block-level
// pair pool + in-kernel exact, zero atomics, deterministic).
// Round 13: exact pass fused into interp (removes kernel 4, worklist bufs,
// x re-read, one dispatch; exact chains run from block-staged LDS tables).

#define TB 3.0f
#define NB 32
#define NC 8
#define NL 8
#define LN2 0.69314718055994530942f

#define GX0 -6.5f
#define GX1 6.5f
#define TZ 0.5f
#define TL 0.5f

#define PT_FLOATS (64 * 99)                  // 6336: 64 tables of 33|33|33
#define GP_FLOATS (PT_FLOATS + 72 + 72 + 8)  // + Sc | Bb | LJ  (6488 floats)
#define GP_BYTES  (GP_FLOATS * 4)            // 25952
#define TAB_OFF   26112                      // 64B-aligned (64*408)
#define CAP 256                              // pair pool per block

__device__ __forceinline__ float softplusf(float v) {
    return fmaxf(v, 0.f) + log1pf(expf(-fabsf(v)));
}

__device__ __forceinline__ unsigned short f2h(float f) {
    _Float16 h = (_Float16)f;
    unsigned short u;
    __builtin_memcpy(&u, &h, 2);
    return u;
}
__device__ __forceinline__ float h2f(unsigned short u) {
    _Float16 h;
    __builtin_memcpy(&h, &u, 2);
    return (float)h;
}

__device__ __forceinline__ int bsearch32(const float* __restrict__ E, float xc) {
    int i = (xc >= E[16]) ? 16 : 0;
    i += (xc >= E[i + 8]) ? 8 : 0;
    i += (xc >= E[i + 4]) ? 4 : 0;
    i += (xc >= E[i + 2]) ? 2 : 0;
    i += (xc >= E[i + 1]) ? 1 : 0;
    return i;
}

// Tlc: [0..32] cumw edges, [33..65] cumh, [66..98] derivs (LDS or global)
__device__ __forceinline__ void spline_eval(const float* __restrict__ Tlc,
                                            float zc, float& zo, float& ldo) {
    const float* E  = Tlc;
    const float* Hc = Tlc + 33;
    const float* Dv = Tlc + 66;

    float xc = fminf(fmaxf(zc, -TB), TB);
    int i = bsearch32(E, xc);

    float xk  = E[i],  xk1 = E[i + 1];
    float yk  = Hc[i], yk1 = Hc[i + 1];
    float dk  = Dv[i], dk1 = Dv[i + 1];

    float wk    = xk1 - xk;
    float hk    = yk1 - yk;
    float invw  = __builtin_amdgcn_rcpf(wk);
    float delta = hk * invw;
    float th    = (xc - xk) * invw;
    float omt   = 1.f - th;
    float t1m   = th * omt;
    float th2   = th * th;

    float num    = hk * fmaf(delta, th2, dk * t1m);
    float den    = fmaf(fmaf(-2.f, delta, dk + dk1), t1m, delta);
    float invden = __builtin_amdgcn_rcpf(den);
    float y      = fmaf(num, invden, yk);

    float dt    = delta * t1m;
    float inner = fmaf(dk1, th2, fmaf(dk, omt * omt, dt + dt));
    float dnum  = (delta * delta) * inner;
    float r  = dnum * invden * invden;
    float ld = LN2 * __builtin_amdgcn_logf(r);

    bool inside = (zc >= -TB) && (zc <= TB);
    zo  = inside ? y : zc;
    ldo = inside ? ld : 0.f;
}

// exact chain for one (x, channel) from LDS-staged T
__device__ __forceinline__ void exact_chain(const float* __restrict__ T,
                                            float xv, int c,
                                            float& zout, float& lout) {
    const float* ScT = T + PT_FLOATS;
    const float* BbT = ScT + 72;
    const float* LJT = BbT + 72;
    float zc = xv;
    float lacc = LJT[c];
#pragma unroll 1
    for (int l = 0; l < NL; ++l) {
        zc = (zc - BbT[l * 8 + c]) * ScT[l * 8 + c];
        float ld;
        spline_eval(T + (l * 8 + c) * 99, zc, zc, ld);
        lacc += ld;
    }
    zout = (zc - BbT[NL * 8 + c]) * ScT[NL * 8 + c];
    lout = lacc;
}

// ---------------- kernel 1: build tables once -> gparam ----------------
extern "C" __global__ void __launch_bounds__(256)
build_tables(const float* __restrict__ w, const float* __restrict__ h,
             const float* __restrict__ s, const float* __restrict__ bias,
             const float* __restrict__ lsc, float* __restrict__ gparam)
{
    __shared__ float T[PT_FLOATS];
    __shared__ float Sc[72], Bb[72], LJ[8];

    const int tid = threadIdx.x;

    if (tid < 64) {                       // widths -> cumw edges
        const int l = tid >> 3, c = tid & 7;
        float* cw = &T[tid * 99];
        const float* wr = w + (l * NC + c) * NB;
        float m = wr[0];
        for (int b = 1; b < NB; ++b) m = fmaxf(m, wr[b]);
        float sum = 0.f;
        for (int b = 0; b < NB; ++b) sum += expf(wr[b] - m);
        float inv = 1.f / sum;
        float acc = 0.f;
        cw[0] = -TB;
        for (int b = 0; b < NB; ++b) {
            acc += 1e-3f + (1.f - 1e-3f * NB) * (expf(wr[b] - m) * inv);
            cw[b + 1] = 6.f * acc - 3.f;
        }
        cw[NB] = TB;
    } else if (tid < 128) {               // heights -> cumh
        const int t = tid - 64;
        float* ch = &T[t * 99 + 33];
        const int l = t >> 3, c = t & 7;
        const float* hr = h + (l * NC + c) * NB;
        float m = hr[0];
        for (int b = 1; b < NB; ++b) m = fmaxf(m, hr[b]);
        float sum = 0.f;
        for (int b = 0; b < NB; ++b) sum += expf(hr[b] - m);
        float inv = 1.f / sum;
        float acc = 0.f;
        ch[0] = -TB;
        for (int b = 0; b < NB; ++b) {
            acc += 1e-3f + (1.f - 1e-3f * NB) * (expf(hr[b] - m) * inv);
            ch[b + 1] = 6.f * acc - 3.f;
        }
        ch[NB] = TB;
    } else if (tid < 192) {               // derivs
        const int t = tid - 128;
        const int l = t >> 3, c = t & 7;
        float* dv = &T[t * 99 + 66];
        const float* sr = s + (l * NC + c) * (NB - 1);
        const float cst = logf(expm1f(1.f - 1e-3f));
        const float dbound = 1e-3f + softplusf(cst);
        dv[0]  = dbound;
        dv[NB] = dbound;
        for (int k = 0; k < NB - 1; ++k)
            dv[k + 1] = 1e-3f + softplusf(sr[k]);
    }
    if (tid < 72) { Sc[tid] = expf(-lsc[tid]); Bb[tid] = bias[tid]; }
    if (tid < 8) {
        float a = 0.f;
        for (int l = 0; l <= NL; ++l) a += lsc[l * NC + tid];
        LJ[tid] = -a;
    }
    __syncthreads();

    for (int k = tid; k < PT_FLOATS; k += 256) gparam[k] = T[k];
    if (tid < 72) gparam[PT_FLOATS + tid]       = Sc[tid];
    if (tid < 72) gparam[PT_FLOATS + 72 + tid]  = Bb[tid];
    if (tid < 8)  gparam[PT_FLOATS + 144 + tid] = LJ[tid];
}

// ------- kernel 2: grid eval, 1 thread per grid point (8 ch serial) --------
// Block covers 256 points with 1 overlap: rows [b*255, b*255+254] written.
extern "C" __global__ void __launch_bounds__(256)
grid_eval(const float* __restrict__ gparam, char* __restrict__ tabb,
          int G, float dx)
{
    __shared__ float T[GP_FLOATS];
    __shared__ unsigned short ZL[256 * 16];   // h(z)[8] | h(lj)[8] per thread
    for (int k = threadIdx.x; k < GP_FLOATS; k += 256) T[k] = gparam[k];
    __syncthreads();
    const float* ScT = T + PT_FLOATS;
    const float* BbT = ScT + 72;
    const float* LJT = BbT + 72;

    const int t  = threadIdx.x;
    const int p0 = blockIdx.x * 255;
    const int i  = min(p0 + t, G - 1);

    const float xv = fmaf((float)i, dx, GX0);
    float z[NC], lj[NC];
#pragma unroll
    for (int c = 0; c < NC; ++c) { z[c] = xv; lj[c] = LJT[c]; }

#pragma unroll 1
    for (int l = 0; l < NL; ++l) {
        const float* Tl = T + l * NC * 99;
#pragma unroll
        for (int c = 0; c < NC; ++c) {
            float u = (z[c] - BbT[l * 8 + c]) * ScT[l * 8 + c];
            float zo, ld;
            spline_eval(Tl + c * 99, u, zo, ld);
            z[c] = zo;
            lj[c] += ld;
        }
    }
    unsigned short zh[NC], lh[NC];
#pragma unroll
    for (int c = 0; c < NC; ++c) {
        z[c] = (z[c] - BbT[NL * 8 + c]) * ScT[NL * 8 + c];
        zh[c] = f2h(z[c]);
        lh[c] = f2h(lj[c]);
        ZL[t * 16 + c]     = zh[c];
        ZL[t * 16 + 8 + c] = lh[c];
    }
    __syncthreads();

    const int r = p0 + t;
    if (t < 255 && r <= G - 2) {
        ushort4* rowp = (ushort4*)(tabb + (size_t)r * 64);
#pragma unroll
        for (int c = 0; c < NC; ++c) {
            const float zn  = h2f(ZL[(t + 1) * 16 + c]);
            const float ljn = h2f(ZL[(t + 1) * 16 + 8 + c]);
            ushort4 v;
            v.x = zh[c]; v.y = f2h(zn - h2f(zh[c]));
            v.z = lh[c]; v.w = f2h(ljn - h2f(lh[c]));
            rowp[c] = v;
        }
    }
}

// ------- kernel 3: fused interp + in-block exact (no atomics) ---------------
extern "C" __global__ void __launch_bounds__(256)
interp_kernel(const float* __restrict__ x, const char* __restrict__ tabb,
              const float* __restrict__ gparam, float* __restrict__ out,
              int N, int G, float dx, float invdx)
{
    __shared__ float T[GP_FLOATS];
    __shared__ float xbuf[256];
    __shared__ unsigned short pairs[CAP];
    __shared__ float resZ[CAP], resL[CAP];
    __shared__ unsigned wsum[4];

    const int tid  = threadIdx.x;
    const int n    = blockIdx.x * 256 + tid;
    const int lane = tid & 63;
    const int wloc = tid >> 6;
    const bool active = (n < N);

    float xv = 0.f;
    if (active) xv = x[n];
    xbuf[tid] = xv;

    float z[NC], lj[NC];
    int flags = 0;
    if (active) {
        int i = (int)floorf((xv - GX0) * invdx);
        const bool oor = !(xv > GX0 && xv < GX1);
        i = min(max(i, 0), G - 2);
        const float t = (xv - fmaf((float)i, dx, GX0)) * invdx;

        const float4* rp = (const float4*)(tabb + (size_t)i * 64);
        union { float4 q[4]; unsigned int u[16]; } R;
        R.q[0] = rp[0]; R.q[1] = rp[1]; R.q[2] = rp[2]; R.q[3] = rp[3];
#pragma unroll
        for (int c = 0; c < NC; ++c) {
            const unsigned a = R.u[2 * c], b = R.u[2 * c + 1];
            const float z0 = h2f((unsigned short)a);
            const float dz = h2f((unsigned short)(a >> 16));
            const float l0 = h2f((unsigned short)b);
            const float dl = h2f((unsigned short)(b >> 16));
            z[c]  = fmaf(t, dz, z0);
            lj[c] = fmaf(t, dl, l0);
            if (fabsf(dz) > TZ || fabsf(dl) > TL) flags |= (1 << c);
        }
        if (oor) flags = 0xff;
    }

    // ---- collect flagged (point,channel) pairs; deterministic, no atomics --
    unsigned long long m[NC];
    unsigned wtot = 0;
#pragma unroll
    for (int c = 0; c < NC; ++c) {
        m[c] = __ballot((flags >> c) & 1);
        wtot += (unsigned)__popcll(m[c]);
    }
    if (lane == 0) wsum[wloc] = wtot;
    __syncthreads();

    unsigned woff = 0, btot = 0;
#pragma unroll
    for (int j = 0; j < 4; ++j) {
        const unsigned v = wsum[j];
        if (j < wloc) woff += v;
        btot += v;
    }
    const unsigned long long lowmask = (1ull << lane) - 1ull;
    {
        unsigned basec = 0;
#pragma unroll
        for (int c = 0; c < NC; ++c) {
            if ((flags >> c) & 1) {
                const unsigned idx = woff + basec + (unsigned)__popcll(m[c] & lowmask);
                if (idx < CAP) pairs[idx] = (unsigned short)((tid << 3) | c);
            }
            basec += (unsigned)__popcll(m[c]);
        }
    }
    if (btot > 0) {                        // stage tables only when needed
        for (int k = tid; k < GP_FLOATS; k += 256) T[k] = gparam[k];
    }
    __syncthreads();                       // pairs + T visible

    const unsigned pcnt = min(btot, (unsigned)CAP);
    for (unsigned k = tid; k < pcnt; k += 256) {
        const unsigned pr = pairs[k];
        const int stid = (int)(pr >> 3), c = (int)(pr & 7u);
        float zo, lo;
        exact_chain(T, xbuf[stid], c, zo, lo);
        resZ[k] = zo; resL[k] = lo;
    }
    __syncthreads();                       // results visible

    if (active && flags) {
        unsigned basec = 0;
#pragma unroll
        for (int c = 0; c < NC; ++c) {
            if ((flags >> c) & 1) {
                const unsigned idx = woff + basec + (unsigned)__popcll(m[c] & lowmask);
                if (idx < CAP) {
                    z[c] = resZ[idx]; lj[c] = resL[idx];
                } else {                   // pool overflow: inline exact
                    exact_chain(T, xv, c, z[c], lj[c]);
                }
            }
            basec += (unsigned)__popcll(m[c]);
        }
    }

    if (active) {
        float4* oz = (float4*)(out + (size_t)n * NC);
        oz[0] = make_float4(z[0], z[1], z[2], z[3]);
        oz[1] = make_float4(z[4], z[5], z[6], z[7]);
        float4* ol = (float4*)(out + (size_t)N * NC + (size_t)n * NC);
        ol[0] = make_float4(lj[0], lj[1], lj[2], lj[3]);
        ol[1] = make_float4(lj[4], lj[5], lj[6], lj[7]);
    }
}

// ---------------- legacy monolithic kernel (ws-too-small fallback) ----------
extern "C" __global__ void __launch_bounds__(256)
flow_kernel(const float* __restrict__ x, const float* __restrict__ w,
            const float* __restrict__ h, const float* __restrict__ s,
            const float* __restrict__ bias, const float* __restrict__ lsc,
            float* __restrict__ out, int N)
{
    __shared__ float T[PT_FLOATS];
    __shared__ float Bb[NL + 1][NC];
    __shared__ float Sc[NL + 1][NC];
    __shared__ float LJC[NC];

    const int tid = threadIdx.x;
    if (tid < 64) {
        const int l = tid >> 3, c = tid & 7;
        float* cw = &T[tid * 99];
        {
            const float* wr = w + (l * NC + c) * NB;
            float m = wr[0];
            for (int b = 1; b < NB; ++b) m = fmaxf(m, wr[b]);
            float sum = 0.f;
            for (int b = 0; b < NB; ++b) sum += expf(wr[b] - m);
            float inv = 1.f / sum;
            float acc = 0.f;
            cw[0] = -TB;
            for (int b = 0; b < NB; ++b) {
                acc += 1e-3f + (1.f - 1e-3f * NB) * (expf(wr[b] - m) * inv);
                cw[b + 1] = 6.f * acc - 3.f;
            }
            cw[NB] = TB;
        }
        {
            float* ch = cw + 33;
            const float* hr = h + (l * NC + c) * NB;
            float m = hr[0];
            for (int b = 1; b < NB; ++b) m = fmaxf(m, hr[b]);
            float sum = 0.f;
            for (int b = 0; b < NB; ++b) sum += expf(hr[b] - m);
            float inv = 1.f / sum;
            float acc = 0.f;
            ch[0] = -TB;
            for (int b = 0; b < NB; ++b) {
                acc += 1e-3f + (1.f - 1e-3f * NB) * (expf(hr[b] - m) * inv);
                ch[b + 1] = 6.f * acc - 3.f;
            }
            ch[NB] = TB;
        }
        {
            float* dv = cw + 66;
            const float* sr = s + (l * NC + c) * (NB - 1);
            const float cst = logf(expm1f(1.f - 1e-3f));
            const float dbound = 1e-3f + softplusf(cst);
            dv[0]  = dbound;
            dv[NB] = dbound;
            for (int k = 0; k < NB - 1; ++k)
                dv[k + 1] = 1e-3f + softplusf(sr[k]);
        }
    }
    if (tid < (NL + 1) * NC) {
        const int l = tid >> 3, c = tid & 7;
        Bb[l][c] = bias[tid];
        Sc[l][c] = expf(-lsc[tid]);
    }
    if (tid < NC) {
        float a = 0.f;
        for (int l = 0; l <= NL; ++l) a += lsc[l * NC + tid];
        LJC[tid] = -a;
    }
    __syncthreads();

    const int n = blockIdx.x * 256 + tid;
    if (n >= N) return;
    const float xv = x[n];
    float z[NC], lj[NC];
#pragma unroll
    for (int c = 0; c < NC; ++c) { z[c] = xv; lj[c] = LJC[c]; }
#pragma unroll 1
    for (int l = 0; l < NL; ++l) {
        const float* Tl = &T[l * NC * 99];
#pragma unroll
        for (int c = 0; c < NC; ++c) {
            float zc = (z[c] - Bb[l][c]) * Sc[l][c];
            float zo, ld;
            spline_eval(Tl + c * 99, zc, zo, ld);
            z[c] = zo;
            lj[c] += ld;
        }
    }
#pragma unroll
    for (int c = 0; c < NC; ++c) z[c] = (z[c] - Bb[NL][c]) * Sc[NL][c];

    float4* oz = (float4*)(out + (size_t)n * NC);
    oz[0] = make_float4(z[0], z[1], z[2], z[3]);
    oz[1] = make_float4(z[4], z[5], z[6], z[7]);
    float4* ol = (float4*)(out + (size_t)N * NC + (size_t)n * NC);
    ol[0] = make_float4(lj[0], lj[1], lj[2], lj[3]);
    ol[1] = make_float4(lj[4], lj[5], lj[6], lj[7]);
}

extern "C" void kernel_launch(void* const* d_in, const int* in_sizes, int n_in,
                              void* d_out, int out_size, void* d_ws, size_t ws_size,
                              hipStream_t stream) {
    const float* x    = (const float*)d_in[0];
    const float* w    = (const float*)d_in[1];
    const float* h    = (const float*)d_in[2];
    const float* s    = (const float*)d_in[3];
    const float* bias = (const float*)d_in[4];
    const float* lsc  = (const float*)d_in[5];
    float* out = (float*)d_out;
    const int N = in_sizes[0];

    // Layout (bytes): [0,GP_BYTES) gparam | [TAB_OFF,+G*64) packed tab
    int G = 65536;
    while (G > 2048 && ((size_t)TAB_OFF + (size_t)G * 64) > ws_size)
        G >>= 1;
    const size_t need = (size_t)TAB_OFF + (size_t)G * 64;

    if (need <= ws_size) {
        char* basep = (char*)d_ws;
        float* gparam = (float*)basep;
        char*  tabb   = basep + TAB_OFF;

        const float dx = (GX1 - GX0) / (float)(G - 1);
        const int gblocks = (G - 1 + 254) / 255;
        build_tables<<<1, 256, 0, stream>>>(w, h, s, bias, lsc, gparam);
        grid_eval<<<gblocks, 256, 0, stream>>>(gparam, tabb, G, dx);
        interp_kernel<<<(N + 255) / 256, 256, 0, stream>>>(
            x, tabb, gparam, out, N, G, dx, 1.f / dx);
    } else {
        flow_kernel<<<(N + 255) / 256, 256, 0, stream>>>(
            x, w, h, s, bias, lsc, out, N);
    }
}